// Round 1
// baseline (1650.973 us; speedup 1.0000x reference)
//
#include <hip/hip_runtime.h>
#include <math.h>

#define CH 128
#define KSEL 512
#define CAP 4096
#define TOT 2048   // 4*KSEL
#define NEG_INF (-__builtin_inff())

__device__ __forceinline__ float gelu_exact(float v) {
    return v * 0.5f * (1.0f + erff(v * 0.70710678118654752440f));
}

// ---------------- reliability head: rel[b][h][w], border -> -inf ----------------
__global__ __launch_bounds__(256) void rel_kernel(
    const float* __restrict__ fm, const float* __restrict__ w1,
    const float* __restrict__ b1, const float* __restrict__ w2,
    const float* __restrict__ b2, float* __restrict__ rel,
    int H, int W, int border)
{
    int HW = H * W;
    int gid = blockIdx.x * blockDim.x + threadIdx.x;
    if (gid >= 2 * HW) return;
    int b = gid / HW;
    int p = gid - b * HW;
    int y = p / W, x = p - y * W;
    bool interior = (y >= border) && (y < H - border) && (x >= border) && (x < W - border);
    if (!interior) { rel[gid] = NEG_INF; return; }

    const float* xb = fm + (size_t)b * CH * HW + p;
    float xv[CH];
    #pragma unroll
    for (int c = 0; c < CH; ++c) xv[c] = xb[(size_t)c * HW];

    float acc = b2[0];
    for (int o = 0; o < CH; ++o) {
        const float* wr = w1 + o * CH;
        float h = b1[o];
        #pragma unroll
        for (int c = 0; c < CH; ++c) h = fmaf(wr[c], xv[c], h);
        acc = fmaf(w2[o], gelu_exact(h), acc);
    }
    rel[gid] = acc;
}

// ---------------- separable max-pool pieces ----------------
__global__ __launch_bounds__(256) void rowmax_kernel(
    const float* __restrict__ in, float* __restrict__ out, int H, int W, int r)
{
    int HW = H * W;
    int gid = blockIdx.x * blockDim.x + threadIdx.x;
    if (gid >= 2 * HW) return;
    int b = gid / HW, p = gid - b * HW;
    int y = p / W, x = p - y * W;
    const float* row = in + (size_t)b * HW + (size_t)y * W;
    int lo = x - r; if (lo < 0) lo = 0;
    int hi = x + r; if (hi > W - 1) hi = W - 1;
    float m = NEG_INF;
    for (int xx = lo; xx <= hi; ++xx) m = fmaxf(m, row[xx]);
    out[gid] = m;
}

__device__ __forceinline__ float colmax_at(const float* t, int b, int HW, int H, int W,
                                           int y, int x, int r)
{
    int lo = y - r; if (lo < 0) lo = 0;
    int hi = y + r; if (hi > H - 1) hi = H - 1;
    const float* col = t + (size_t)b * HW + x;
    float m = NEG_INF;
    for (int yy = lo; yy <= hi; ++yy) m = fmaxf(m, col[(size_t)yy * W]);
    return m;
}

// maskf = (rel == maxpool(rel))
__global__ __launch_bounds__(256) void colmax_init_kernel(
    const float* __restrict__ tmp, const float* __restrict__ rel,
    float* __restrict__ maskf, int H, int W, int r)
{
    int HW = H * W;
    int gid = blockIdx.x * blockDim.x + threadIdx.x;
    if (gid >= 2 * HW) return;
    int b = gid / HW, p = gid - b * HW;
    int y = p / W, x = p - y * W;
    float m = colmax_at(tmp, b, HW, H, W, y, x, r);
    maskf[gid] = (rel[gid] == m) ? 1.0f : 0.0f;
}

// supp = maxpool(maskf) > 0 ; suppw = supp ? -inf : rel ; suppm = supp
__global__ __launch_bounds__(256) void colmax_suppw_kernel(
    const float* __restrict__ tmp, const float* __restrict__ rel,
    float* __restrict__ suppw, float* __restrict__ suppm, int H, int W, int r)
{
    int HW = H * W;
    int gid = blockIdx.x * blockDim.x + threadIdx.x;
    if (gid >= 2 * HW) return;
    int b = gid / HW, p = gid - b * HW;
    int y = p / W, x = p - y * W;
    float m = colmax_at(tmp, b, HW, H, W, y, x, r);
    bool supp = m > 0.0f;
    suppw[gid] = supp ? NEG_INF : rel[gid];
    suppm[gid] = supp ? 1.0f : 0.0f;
}

// maskf |= (suppw == maxpool(suppw)) & !supp
__global__ __launch_bounds__(256) void colmax_new_kernel(
    const float* __restrict__ tmp, const float* __restrict__ suppw,
    const float* __restrict__ suppm, float* __restrict__ maskf, int H, int W, int r)
{
    int HW = H * W;
    int gid = blockIdx.x * blockDim.x + threadIdx.x;
    if (gid >= 2 * HW) return;
    int b = gid / HW, p = gid - b * HW;
    int y = p / W, x = p - y * W;
    float m = colmax_at(tmp, b, HW, H, W, y, x, r);
    if ((suppw[gid] == m) && (suppm[gid] == 0.0f)) maskf[gid] = 1.0f;
}

// ---------------- compaction of finite maxima ----------------
__global__ __launch_bounds__(256) void compact_kernel(
    const float* __restrict__ rel, const float* __restrict__ maskf, int HW,
    float* __restrict__ lval, int* __restrict__ lidx, int* __restrict__ counts, int s)
{
    int gid = blockIdx.x * blockDim.x + threadIdx.x;
    if (gid >= 2 * HW) return;
    int b = gid / HW, p = gid - b * HW;
    float v = rel[gid];
    if (maskf[gid] > 0.0f && !isinf(v)) {
        int bs = b * 4 + s;
        int slot = atomicAdd(&counts[bs], 1);
        if (slot < CAP) { lval[bs * CAP + slot] = v; lidx[bs * CAP + slot] = p; }
    }
}

// ---------------- per-(b,scale) bitonic sort + top-K ----------------
__global__ __launch_bounds__(256) void sort_topk_kernel(
    const float* __restrict__ lval, const int* __restrict__ lidx,
    const int* __restrict__ counts, float* __restrict__ tv, int* __restrict__ ti)
{
    __shared__ float sv[CAP];
    __shared__ int   si[CAP];
    int bs = blockIdx.x;
    int M = counts[bs]; if (M > CAP) M = CAP;
    for (int i = threadIdx.x; i < CAP; i += 256) {
        if (i < M) { sv[i] = lval[bs * CAP + i]; si[i] = lidx[bs * CAP + i]; }
        else       { sv[i] = NEG_INF;            si[i] = 0x7FFFFFFF; }
    }
    __syncthreads();
    for (int k = 2; k <= CAP; k <<= 1) {
        for (int j = k >> 1; j > 0; j >>= 1) {
            for (int t = threadIdx.x; t < CAP; t += 256) {
                int p = t ^ j;
                if (p > t) {
                    float va = sv[t], vb = sv[p];
                    int   ia = si[t], ib = si[p];
                    bool aBefore = (va > vb) || (va == vb && ia < ib);
                    bool up = ((t & k) == 0);
                    if (up ? !aBefore : aBefore) {
                        sv[t] = vb; sv[p] = va; si[t] = ib; si[p] = ia;
                    }
                }
            }
            __syncthreads();
        }
    }
    for (int j = threadIdx.x; j < KSEL; j += 256) {
        if (j < M) { tv[bs * KSEL + j] = sv[j]; ti[bs * KSEL + j] = si[j]; }
        else       { tv[bs * KSEL + j] = NEG_INF; ti[bs * KSEL + j] = j - M; }
    }
}

// ---------------- coords + reliability outputs ----------------
__global__ __launch_bounds__(256) void coords_kernel(
    const float* __restrict__ tv, const int* __restrict__ ti, float* __restrict__ out)
{
    int gid = blockIdx.x * blockDim.x + threadIdx.x;
    if (gid >= 8 * KSEL) return;
    int bs = gid / KSEL, k = gid - bs * KSEL;
    int b = bs >> 2, s = bs & 3;
    int W = 512 >> s;
    int idx = ti[gid];
    int y = idx / W, x = idx - y * W;
    float nx = (float)x / (float)(W - 1) * 2.0f - 1.0f;
    float ny = (float)y / (float)(W - 1) * 2.0f - 1.0f;
    int pos = s * KSEL + k;
    out[((size_t)b * TOT + pos) * 2 + 0] = nx;
    out[((size_t)b * TOT + pos) * 2 + 1] = ny;
    out[2 * TOT * 2 + (size_t)b * TOT + pos] = tv[gid];
}

// ---------------- gathered projection head + bilinear combine ----------------
__global__ __launch_bounds__(128) void feats_kernel(
    const float* __restrict__ fm0, const float* __restrict__ fm1,
    const float* __restrict__ fm2, const float* __restrict__ fm3,
    const float* __restrict__ w1, const float* __restrict__ b1,
    const float* __restrict__ w2, const float* __restrict__ b2,
    const int* __restrict__ ti, float* __restrict__ out)
{
    int blk = blockIdx.x;             // 0..4095 = (b*4+s)*KSEL + k
    int bs = blk / KSEL, k = blk - bs * KSEL;
    int b = bs >> 2, s = bs & 3;
    int W = 512 >> s, H = W, HW = H * W;
    const float* fm = (s == 0) ? fm0 : (s == 1) ? fm1 : (s == 2) ? fm2 : fm3;

    int idx = ti[bs * KSEL + k];
    int yi0 = idx / W, xi0 = idx - yi0 * W;
    float nx = (float)xi0 / (float)(W - 1) * 2.0f - 1.0f;
    float ny = (float)yi0 / (float)(H - 1) * 2.0f - 1.0f;
    float ix = ((nx + 1.0f) * (float)W - 1.0f) * 0.5f;
    float iy = ((ny + 1.0f) * (float)H - 1.0f) * 0.5f;
    float x0 = floorf(ix), y0 = floorf(iy);
    float x1 = x0 + 1.0f,  y1 = y0 + 1.0f;
    float wx1 = ix - x0, wy1 = iy - y0;

    float xs[4]  = {x0, x1, x0, x1};
    float ysv[4] = {y0, y0, y1, y1};
    float wn[4]  = {(1.0f - wx1) * (1.0f - wy1), wx1 * (1.0f - wy1),
                    (1.0f - wx1) * wy1,          wx1 * wy1};
    int pix[4]; float wv[4];
    #pragma unroll
    for (int n = 0; n < 4; ++n) {
        bool valid = (xs[n] >= 0.0f) && (xs[n] <= (float)(W - 1)) &&
                     (ysv[n] >= 0.0f) && (ysv[n] <= (float)(H - 1));
        int xc = (int)fminf(fmaxf(xs[n], 0.0f), (float)(W - 1));
        int yc = (int)fminf(fmaxf(ysv[n], 0.0f), (float)(H - 1));
        pix[n] = yc * W + xc;
        wv[n] = valid ? wn[n] : 0.0f;
    }

    __shared__ float xls[4][CH];
    __shared__ float hmix[CH];
    int o = threadIdx.x;
    {
        const float* fb_ = fm + ((size_t)b * CH + o) * HW;
        #pragma unroll
        for (int n = 0; n < 4; ++n) xls[n][o] = fb_[pix[n]];
    }
    __syncthreads();

    float h0 = b1[o], h1 = h0, h2 = h0, h3 = h0;
    const float* wr = w1 + o * CH;
    for (int c = 0; c < CH; ++c) {
        float w = wr[c];
        h0 = fmaf(w, xls[0][c], h0);
        h1 = fmaf(w, xls[1][c], h1);
        h2 = fmaf(w, xls[2][c], h2);
        h3 = fmaf(w, xls[3][c], h3);
    }
    float wsum = wv[0] + wv[1] + wv[2] + wv[3];
    hmix[o] = wv[0] * gelu_exact(h0) + wv[1] * gelu_exact(h1) +
              wv[2] * gelu_exact(h2) + wv[3] * gelu_exact(h3);
    __syncthreads();

    float acc = b2[o] * wsum;
    const float* w2r = w2 + o * CH;
    for (int c = 0; c < CH; ++c) acc = fmaf(w2r[c], hmix[c], acc);
    out[2 * TOT * 2 + 2 * TOT + ((size_t)b * TOT + s * KSEL + k) * CH + o] = acc;
}

// ---------------- host ----------------
extern "C" void kernel_launch(void* const* d_in, const int* in_sizes, int n_in,
                              void* d_out, int out_size, void* d_ws, size_t ws_size,
                              hipStream_t stream)
{
    const float* fm[4] = {(const float*)d_in[0], (const float*)d_in[1],
                          (const float*)d_in[2], (const float*)d_in[3]};
    const float* rw1 = (const float*)d_in[4];
    const float* rb1 = (const float*)d_in[5];
    const float* rw2 = (const float*)d_in[6];
    const float* rb2 = (const float*)d_in[7];
    const float* fw1 = (const float*)d_in[8];
    const float* fb1 = (const float*)d_in[9];
    const float* fw2 = (const float*)d_in[10];
    const float* fb2 = (const float*)d_in[11];

    float* ws = (float*)d_ws;
    // float-offset workspace layout
    float* rel   = ws;                    // 696320
    float* maskf = ws + 696320;           // 696320
    float* tmp   = ws + 1392640;          // 524288
    float* suppw = ws + 1916928;          // 524288
    float* suppm = ws + 2441216;          // 524288
    float* lval  = ws + 2965504;          // 8*CAP
    int*   lidx  = (int*)(ws + 2998272);  // 8*CAP
    int*   counts= (int*)(ws + 3031040);  // 8
    float* tv    = ws + 3031048;          // 8*KSEL
    int*   ti    = (int*)(ws + 3035144);  // 8*KSEL

    hipMemsetAsync(counts, 0, 8 * sizeof(int), stream);

    const size_t rel_off[4] = {0, 524288, 655360, 688128};
    for (int s = 0; s < 4; ++s) {
        int H = 512 >> s, W = H, HW = H * W, N = 2 * HW;
        int r = H / 64; if (r < 1) r = 1;
        int border = r;
        int nb = (N + 255) / 256;
        float* rl = rel + rel_off[s];
        float* mk = maskf + rel_off[s];

        rel_kernel<<<nb, 256, 0, stream>>>(fm[s], rw1, rb1, rw2, rb2, rl, H, W, border);

        rowmax_kernel<<<nb, 256, 0, stream>>>(rl, tmp, H, W, r);
        colmax_init_kernel<<<nb, 256, 0, stream>>>(tmp, rl, mk, H, W, r);
        for (int it = 0; it < 2; ++it) {
            rowmax_kernel<<<nb, 256, 0, stream>>>(mk, tmp, H, W, r);
            colmax_suppw_kernel<<<nb, 256, 0, stream>>>(tmp, rl, suppw, suppm, H, W, r);
            rowmax_kernel<<<nb, 256, 0, stream>>>(suppw, tmp, H, W, r);
            colmax_new_kernel<<<nb, 256, 0, stream>>>(tmp, suppw, suppm, mk, H, W, r);
        }
        compact_kernel<<<nb, 256, 0, stream>>>(rl, mk, HW, lval, lidx, counts, s);
    }

    sort_topk_kernel<<<8, 256, 0, stream>>>(lval, lidx, counts, tv, ti);
    coords_kernel<<<16, 256, 0, stream>>>(tv, ti, (float*)d_out);
    feats_kernel<<<4096, 128, 0, stream>>>(fm[0], fm[1], fm[2], fm[3],
                                           fw1, fb1, fw2, fb2, ti, (float*)d_out);
}

// Round 2
// 884.417 us; speedup vs baseline: 1.8667x; 1.8667x over previous
//
#include <hip/hip_runtime.h>
#include <math.h>

#define CH 128
#define KSEL 512
#define CAP 4096
#define TOT 2048   // 4*KSEL
#define TS 32      // NMS tile
#define NEG_INF (-__builtin_inff())

__device__ __forceinline__ float gelu_exact(float v) {
    return v * 0.5f * (1.0f + erff(v * 0.70710678118654752440f));
}

// ---------------- reliability head as tiled GEMM + fused GELU/layer2 ----------------
// block = 256 threads, 64 pixels; thread = 8 px x 4 och; K chunks of 32.
__global__ __launch_bounds__(256) void rel_gemm_kernel(
    const float* __restrict__ fm, const float* __restrict__ w1,
    const float* __restrict__ b1, const float* __restrict__ w2,
    const float* __restrict__ b2, float* __restrict__ rel,
    int H, int W, int border)
{
    const int HW = H * W;
    __shared__ float xls[128][64];   // [c][px] 32KB
    __shared__ float wt[32][132];    // [c-chunk][och] padded pitch
    __shared__ float w2s[128];

    int tid = threadIdx.x;
    int p0 = blockIdx.x * 64;        // flat base within 2*HW (HW%64==0 -> no b straddle)
    int b  = p0 / HW;
    int pb = p0 - b * HW;
    const float* xbase = fm + (size_t)b * CH * HW + pb;

    // stage x tile: 128 rows x 64 px, float4 coalesced
    #pragma unroll
    for (int pass = 0; pass < 8; ++pass) {
        int c = pass * 16 + (tid >> 4);
        int px4 = (tid & 15) * 4;
        float4 v = *(const float4*)(xbase + (size_t)c * HW + px4);
        *(float4*)&xls[c][px4] = v;
    }
    if (tid < 128) w2s[tid] = w2[tid];

    int och0 = (tid & 31) * 4;
    int px0  = (tid >> 5) * 8;
    float acc[8][4];
    #pragma unroll
    for (int i = 0; i < 8; ++i)
        #pragma unroll
        for (int j = 0; j < 4; ++j) acc[i][j] = b1[och0 + j];

    for (int kc = 0; kc < 128; kc += 32) {
        __syncthreads();
        // stage w chunk transposed: wt[c][och] = w1[och*128 + kc + c]
        #pragma unroll
        for (int pass = 0; pass < 4; ++pass) {
            int och = pass * 32 + (tid >> 3);
            int cc = (tid & 7) * 4;
            float4 v = *(const float4*)(w1 + och * CH + kc + cc);
            wt[cc + 0][och] = v.x; wt[cc + 1][och] = v.y;
            wt[cc + 2][och] = v.z; wt[cc + 3][och] = v.w;
        }
        __syncthreads();
        #pragma unroll
        for (int c = 0; c < 32; ++c) {
            float4 xa = *(const float4*)&xls[kc + c][px0];
            float4 xb = *(const float4*)&xls[kc + c][px0 + 4];
            float4 wv = *(const float4*)&wt[c][och0];
            acc[0][0] = fmaf(xa.x, wv.x, acc[0][0]); acc[0][1] = fmaf(xa.x, wv.y, acc[0][1]);
            acc[0][2] = fmaf(xa.x, wv.z, acc[0][2]); acc[0][3] = fmaf(xa.x, wv.w, acc[0][3]);
            acc[1][0] = fmaf(xa.y, wv.x, acc[1][0]); acc[1][1] = fmaf(xa.y, wv.y, acc[1][1]);
            acc[1][2] = fmaf(xa.y, wv.z, acc[1][2]); acc[1][3] = fmaf(xa.y, wv.w, acc[1][3]);
            acc[2][0] = fmaf(xa.z, wv.x, acc[2][0]); acc[2][1] = fmaf(xa.z, wv.y, acc[2][1]);
            acc[2][2] = fmaf(xa.z, wv.z, acc[2][2]); acc[2][3] = fmaf(xa.z, wv.w, acc[2][3]);
            acc[3][0] = fmaf(xa.w, wv.x, acc[3][0]); acc[3][1] = fmaf(xa.w, wv.y, acc[3][1]);
            acc[3][2] = fmaf(xa.w, wv.z, acc[3][2]); acc[3][3] = fmaf(xa.w, wv.w, acc[3][3]);
            acc[4][0] = fmaf(xb.x, wv.x, acc[4][0]); acc[4][1] = fmaf(xb.x, wv.y, acc[4][1]);
            acc[4][2] = fmaf(xb.x, wv.z, acc[4][2]); acc[4][3] = fmaf(xb.x, wv.w, acc[4][3]);
            acc[5][0] = fmaf(xb.y, wv.x, acc[5][0]); acc[5][1] = fmaf(xb.y, wv.y, acc[5][1]);
            acc[5][2] = fmaf(xb.y, wv.z, acc[5][2]); acc[5][3] = fmaf(xb.y, wv.w, acc[5][3]);
            acc[6][0] = fmaf(xb.z, wv.x, acc[6][0]); acc[6][1] = fmaf(xb.z, wv.y, acc[6][1]);
            acc[6][2] = fmaf(xb.z, wv.z, acc[6][2]); acc[6][3] = fmaf(xb.z, wv.w, acc[6][3]);
            acc[7][0] = fmaf(xb.w, wv.x, acc[7][0]); acc[7][1] = fmaf(xb.w, wv.y, acc[7][1]);
            acc[7][2] = fmaf(xb.w, wv.z, acc[7][2]); acc[7][3] = fmaf(xb.w, wv.w, acc[7][3]);
        }
    }

    float b2v = b2[0];
    float outv[8];
    #pragma unroll
    for (int i = 0; i < 8; ++i) {
        float s = w2s[och0 + 0] * gelu_exact(acc[i][0])
                + w2s[och0 + 1] * gelu_exact(acc[i][1])
                + w2s[och0 + 2] * gelu_exact(acc[i][2])
                + w2s[och0 + 3] * gelu_exact(acc[i][3]);
        #pragma unroll
        for (int m = 16; m; m >>= 1) s += __shfl_xor(s, m);
        outv[i] = s;
    }
    if ((tid & 31) == 0) {
        #pragma unroll
        for (int i = 0; i < 8; ++i) {
            int p = pb + px0 + i;
            int y = p / W, x = p - y * W;
            bool interior = (y >= border) && (y < H - border) &&
                            (x >= border) && (x < W - border);
            rel[p0 + px0 + i] = interior ? (outv[i] + b2v) : NEG_INF;
        }
    }
}

// ---------------- NMS: fused row+col max-pool kernels (replicate-pad == clamped window) --------
__global__ __launch_bounds__(256) void nms_init_kernel(
    const float* __restrict__ rel, float* __restrict__ mask, int H, int W, int r)
{
    int HW = H * W;
    int tpb = (H / TS) * (W / TS);
    int blk = blockIdx.x;
    int b = blk / tpb, t = blk - b * tpb;
    int ty = t / (W / TS), tx = t - ty * (W / TS);
    int L = TS + 2 * r;
    __shared__ float wtile[48][49];
    __shared__ float t1[48][49];
    const float* wp = rel + (size_t)b * HW;
    for (int idx = threadIdx.x; idx < L * L; idx += 256) {
        int i = idx / L, j = idx - i * L;
        int gy = min(max(ty * TS - r + i, 0), H - 1);
        int gx = min(max(tx * TS - r + j, 0), W - 1);
        wtile[i][j] = wp[gy * W + gx];
    }
    __syncthreads();
    for (int idx = threadIdx.x; idx < L * TS; idx += 256) {
        int i = idx / TS, j = idx - i * TS;
        float m = wtile[i][j];
        for (int d = 1; d <= 2 * r; ++d) m = fmaxf(m, wtile[i][j + d]);
        t1[i][j] = m;
    }
    __syncthreads();
    for (int idx = threadIdx.x; idx < TS * TS; idx += 256) {
        int i = idx / TS, j = idx - i * TS;
        float m = t1[i][j];
        for (int d = 1; d <= 2 * r; ++d) m = fmaxf(m, t1[i + d][j]);
        mask[(size_t)b * HW + (ty * TS + i) * W + (tx * TS + j)] =
            (wtile[i + r][j + r] == m) ? 1.0f : 0.0f;
    }
}

// supp = pool(mask) > 0; suppw = supp ? -inf : rel; suppm = supp
__global__ __launch_bounds__(256) void nms_iterA_kernel(
    const float* __restrict__ rel, const float* __restrict__ mask,
    float* __restrict__ suppw, float* __restrict__ suppm, int H, int W, int r)
{
    int HW = H * W;
    int tpb = (H / TS) * (W / TS);
    int blk = blockIdx.x;
    int b = blk / tpb, t = blk - b * tpb;
    int ty = t / (W / TS), tx = t - ty * (W / TS);
    int L = TS + 2 * r;
    __shared__ float wtile[48][49];
    __shared__ float t1[48][49];
    const float* mp = mask + (size_t)b * HW;
    for (int idx = threadIdx.x; idx < L * L; idx += 256) {
        int i = idx / L, j = idx - i * L;
        int gy = min(max(ty * TS - r + i, 0), H - 1);
        int gx = min(max(tx * TS - r + j, 0), W - 1);
        wtile[i][j] = mp[gy * W + gx];
    }
    __syncthreads();
    for (int idx = threadIdx.x; idx < L * TS; idx += 256) {
        int i = idx / TS, j = idx - i * TS;
        float m = wtile[i][j];
        for (int d = 1; d <= 2 * r; ++d) m = fmaxf(m, wtile[i][j + d]);
        t1[i][j] = m;
    }
    __syncthreads();
    for (int idx = threadIdx.x; idx < TS * TS; idx += 256) {
        int i = idx / TS, j = idx - i * TS;
        float m = t1[i][j];
        for (int d = 1; d <= 2 * r; ++d) m = fmaxf(m, t1[i + d][j]);
        size_t g = (size_t)b * HW + (ty * TS + i) * W + (tx * TS + j);
        bool sup = m > 0.0f;
        suppm[g] = sup ? 1.0f : 0.0f;
        suppw[g] = sup ? NEG_INF : rel[g];
    }
}

// mask |= (suppw == pool(suppw)) & !supp ; optionally compact candidates
__global__ __launch_bounds__(256) void nms_iterB_kernel(
    const float* __restrict__ rel, const float* __restrict__ suppw,
    const float* __restrict__ suppm, float* __restrict__ mask,
    int H, int W, int r, int do_compact, int s,
    float* __restrict__ lval, int* __restrict__ lidx, int* __restrict__ counts)
{
    int HW = H * W;
    int tpb = (H / TS) * (W / TS);
    int blk = blockIdx.x;
    int b = blk / tpb, t = blk - b * tpb;
    int ty = t / (W / TS), tx = t - ty * (W / TS);
    int L = TS + 2 * r;
    __shared__ float wtile[48][49];
    __shared__ float t1[48][49];
    const float* sp = suppw + (size_t)b * HW;
    for (int idx = threadIdx.x; idx < L * L; idx += 256) {
        int i = idx / L, j = idx - i * L;
        int gy = min(max(ty * TS - r + i, 0), H - 1);
        int gx = min(max(tx * TS - r + j, 0), W - 1);
        wtile[i][j] = sp[gy * W + gx];
    }
    __syncthreads();
    for (int idx = threadIdx.x; idx < L * TS; idx += 256) {
        int i = idx / TS, j = idx - i * TS;
        float m = wtile[i][j];
        for (int d = 1; d <= 2 * r; ++d) m = fmaxf(m, wtile[i][j + d]);
        t1[i][j] = m;
    }
    __syncthreads();
    for (int idx = threadIdx.x; idx < TS * TS; idx += 256) {
        int i = idx / TS, j = idx - i * TS;
        float m = t1[i][j];
        for (int d = 1; d <= 2 * r; ++d) m = fmaxf(m, t1[i + d][j]);
        int p = (ty * TS + i) * W + (tx * TS + j);
        size_t g = (size_t)b * HW + p;
        bool newm = (wtile[i + r][j + r] == m) && (suppm[g] == 0.0f);
        bool fin = (mask[g] > 0.0f) || newm;
        if (!do_compact) {
            mask[g] = fin ? 1.0f : 0.0f;
        } else if (fin) {
            float v = rel[g];
            if (!isinf(v)) {
                int bs = b * 4 + s;
                int slot = atomicAdd(&counts[bs], 1);
                if (slot < CAP) { lval[bs * CAP + slot] = v; lidx[bs * CAP + slot] = p; }
            }
        }
    }
}

// ---------------- per-(b,scale) bitonic sort + top-K ----------------
__global__ __launch_bounds__(256) void sort_topk_kernel(
    const float* __restrict__ lval, const int* __restrict__ lidx,
    const int* __restrict__ counts, float* __restrict__ tv, int* __restrict__ ti)
{
    __shared__ float sv[CAP];
    __shared__ int   si[CAP];
    int bs = blockIdx.x;
    int M = counts[bs]; if (M > CAP) M = CAP;
    for (int i = threadIdx.x; i < CAP; i += 256) {
        if (i < M) { sv[i] = lval[bs * CAP + i]; si[i] = lidx[bs * CAP + i]; }
        else       { sv[i] = NEG_INF;            si[i] = 0x7FFFFFFF; }
    }
    __syncthreads();
    for (int k = 2; k <= CAP; k <<= 1) {
        for (int j = k >> 1; j > 0; j >>= 1) {
            for (int t = threadIdx.x; t < CAP; t += 256) {
                int p = t ^ j;
                if (p > t) {
                    float va = sv[t], vb = sv[p];
                    int   ia = si[t], ib = si[p];
                    bool aBefore = (va > vb) || (va == vb && ia < ib);
                    bool up = ((t & k) == 0);
                    if (up ? !aBefore : aBefore) {
                        sv[t] = vb; sv[p] = va; si[t] = ib; si[p] = ia;
                    }
                }
            }
            __syncthreads();
        }
    }
    for (int j = threadIdx.x; j < KSEL; j += 256) {
        if (j < M) { tv[bs * KSEL + j] = sv[j]; ti[bs * KSEL + j] = si[j]; }
        else       { tv[bs * KSEL + j] = NEG_INF; ti[bs * KSEL + j] = j - M; }
    }
}

// ---------------- coords + reliability outputs ----------------
__global__ __launch_bounds__(256) void coords_kernel(
    const float* __restrict__ tv, const int* __restrict__ ti, float* __restrict__ out)
{
    int gid = blockIdx.x * blockDim.x + threadIdx.x;
    if (gid >= 8 * KSEL) return;
    int bs = gid / KSEL, k = gid - bs * KSEL;
    int b = bs >> 2, s = bs & 3;
    int W = 512 >> s;
    int idx = ti[gid];
    int y = idx / W, x = idx - y * W;
    float nx = (float)x / (float)(W - 1) * 2.0f - 1.0f;
    float ny = (float)y / (float)(W - 1) * 2.0f - 1.0f;
    int pos = s * KSEL + k;
    out[((size_t)b * TOT + pos) * 2 + 0] = nx;
    out[((size_t)b * TOT + pos) * 2 + 1] = ny;
    out[2 * TOT * 2 + (size_t)b * TOT + pos] = tv[gid];
}

// ---------------- gathered projection head + bilinear combine ----------------
__global__ __launch_bounds__(128) void feats_kernel(
    const float* __restrict__ fm0, const float* __restrict__ fm1,
    const float* __restrict__ fm2, const float* __restrict__ fm3,
    const float* __restrict__ w1, const float* __restrict__ b1,
    const float* __restrict__ w2, const float* __restrict__ b2,
    const int* __restrict__ ti, float* __restrict__ out)
{
    int blk = blockIdx.x;             // (b*4+s)*KSEL + k
    int bs = blk / KSEL, k = blk - bs * KSEL;
    int b = bs >> 2, s = bs & 3;
    int W = 512 >> s, H = W, HW = H * W;
    const float* fm = (s == 0) ? fm0 : (s == 1) ? fm1 : (s == 2) ? fm2 : fm3;

    int idx = ti[bs * KSEL + k];
    int yi0 = idx / W, xi0 = idx - yi0 * W;
    float nx = (float)xi0 / (float)(W - 1) * 2.0f - 1.0f;
    float ny = (float)yi0 / (float)(H - 1) * 2.0f - 1.0f;
    float ix = ((nx + 1.0f) * (float)W - 1.0f) * 0.5f;
    float iy = ((ny + 1.0f) * (float)H - 1.0f) * 0.5f;
    float x0 = floorf(ix), y0 = floorf(iy);
    float x1 = x0 + 1.0f,  y1 = y0 + 1.0f;
    float wx1 = ix - x0, wy1 = iy - y0;

    float xs[4]  = {x0, x1, x0, x1};
    float ysv[4] = {y0, y0, y1, y1};
    float wn[4]  = {(1.0f - wx1) * (1.0f - wy1), wx1 * (1.0f - wy1),
                    (1.0f - wx1) * wy1,          wx1 * wy1};
    int pix[4]; float wv[4];
    #pragma unroll
    for (int n = 0; n < 4; ++n) {
        bool valid = (xs[n] >= 0.0f) && (xs[n] <= (float)(W - 1)) &&
                     (ysv[n] >= 0.0f) && (ysv[n] <= (float)(H - 1));
        int xc = (int)fminf(fmaxf(xs[n], 0.0f), (float)(W - 1));
        int yc = (int)fminf(fmaxf(ysv[n], 0.0f), (float)(H - 1));
        pix[n] = yc * W + xc;
        wv[n] = valid ? wn[n] : 0.0f;
    }

    __shared__ float xls[4][CH];
    __shared__ float hmix[CH];
    int o = threadIdx.x;
    {
        const float* fb_ = fm + ((size_t)b * CH + o) * HW;
        #pragma unroll
        for (int n = 0; n < 4; ++n) xls[n][o] = fb_[pix[n]];
    }
    __syncthreads();

    float h0 = b1[o], h1 = h0, h2 = h0, h3 = h0;
    const float* wr = w1 + o * CH;
    for (int c = 0; c < CH; ++c) {
        float w = wr[c];
        h0 = fmaf(w, xls[0][c], h0);
        h1 = fmaf(w, xls[1][c], h1);
        h2 = fmaf(w, xls[2][c], h2);
        h3 = fmaf(w, xls[3][c], h3);
    }
    float wsum = wv[0] + wv[1] + wv[2] + wv[3];
    hmix[o] = wv[0] * gelu_exact(h0) + wv[1] * gelu_exact(h1) +
              wv[2] * gelu_exact(h2) + wv[3] * gelu_exact(h3);
    __syncthreads();

    float acc = b2[o] * wsum;
    const float* w2r = w2 + o * CH;
    for (int c = 0; c < CH; ++c) acc = fmaf(w2r[c], hmix[c], acc);
    out[2 * TOT * 2 + 2 * TOT + ((size_t)b * TOT + s * KSEL + k) * CH + o] = acc;
}

// ---------------- host ----------------
extern "C" void kernel_launch(void* const* d_in, const int* in_sizes, int n_in,
                              void* d_out, int out_size, void* d_ws, size_t ws_size,
                              hipStream_t stream)
{
    const float* fm[4] = {(const float*)d_in[0], (const float*)d_in[1],
                          (const float*)d_in[2], (const float*)d_in[3]};
    const float* rw1 = (const float*)d_in[4];
    const float* rb1 = (const float*)d_in[5];
    const float* rw2 = (const float*)d_in[6];
    const float* rb2 = (const float*)d_in[7];
    const float* fw1 = (const float*)d_in[8];
    const float* fb1 = (const float*)d_in[9];
    const float* fw2 = (const float*)d_in[10];
    const float* fb2 = (const float*)d_in[11];

    float* ws = (float*)d_ws;
    // per-scale reused buffers (sized for s=0: 2*512*512)
    float* rel   = ws;                     // 524288
    float* mask  = ws + 524288;            // 524288
    float* suppw = ws + 1048576;           // 524288
    float* suppm = ws + 1572864;           // 524288
    float* lval  = ws + 2097152;           // 8*CAP
    int*   lidx  = (int*)(ws + 2129920);   // 8*CAP
    int*   counts= (int*)(ws + 2162688);   // 8
    float* tv    = ws + 2162696;           // 8*KSEL
    int*   ti    = (int*)(ws + 2166792);   // 8*KSEL

    hipMemsetAsync(counts, 0, 8 * sizeof(int), stream);

    for (int s = 0; s < 4; ++s) {
        int H = 512 >> s, W = H, HW = H * W;
        int r = H / 64; if (r < 1) r = 1;
        int border = r;
        int nmsb = 2 * (H / TS) * (W / TS);

        rel_gemm_kernel<<<2 * HW / 64, 256, 0, stream>>>(fm[s], rw1, rb1, rw2, rb2,
                                                         rel, H, W, border);
        nms_init_kernel<<<nmsb, 256, 0, stream>>>(rel, mask, H, W, r);
        nms_iterA_kernel<<<nmsb, 256, 0, stream>>>(rel, mask, suppw, suppm, H, W, r);
        nms_iterB_kernel<<<nmsb, 256, 0, stream>>>(rel, suppw, suppm, mask, H, W, r,
                                                   0, s, lval, lidx, counts);
        nms_iterA_kernel<<<nmsb, 256, 0, stream>>>(rel, mask, suppw, suppm, H, W, r);
        nms_iterB_kernel<<<nmsb, 256, 0, stream>>>(rel, suppw, suppm, mask, H, W, r,
                                                   1, s, lval, lidx, counts);
    }

    sort_topk_kernel<<<8, 256, 0, stream>>>(lval, lidx, counts, tv, ti);
    coords_kernel<<<16, 256, 0, stream>>>(tv, ti, (float*)d_out);
    feats_kernel<<<4096, 128, 0, stream>>>(fm[0], fm[1], fm[2], fm[3],
                                           fw1, fb1, fw2, fb2, ti, (float*)d_out);
}